// Round 2
// baseline (690.328 us; speedup 1.0000x reference)
//
#include <hip/hip_runtime.h>
#include <math.h>

#define BB_  1024
#define NN_  256
#define MM_  128
#define PP_  64
#define KKc  128   // N - M

// ---------------------------------------------------------------------------
// k_pre2: QfQn = Qf@Qn (256x128) | WfQn[c][r] = sum_n Wf[n][c]Qn[n][r] (64x128)
//         bb = parms@Bp.T (1024x128) | QrT[m][n] = Qr[n][m] (128x256)
// ---------------------------------------------------------------------------
__global__ __launch_bounds__(256) void k_pre2(
    const float* __restrict__ Qf, const float* __restrict__ Qn,
    const float* __restrict__ Wf, const float* __restrict__ parms,
    const float* __restrict__ Bp, const float* __restrict__ Qr,
    float* __restrict__ QfQn, float* __restrict__ WfQn,
    float* __restrict__ bb, float* __restrict__ QrT)
{
  const int w = blockIdx.x, tid = threadIdx.x;
  if (w < 128) {
    __shared__ float arow[2][NN_];
    const int n0 = 2 * w;
    for (int idx = tid; idx < 2 * NN_; idx += 256)
      arow[idx >> 8][idx & 255] = Qf[(n0 + (idx >> 8)) * NN_ + (idx & 255)];
    __syncthreads();
    const int r = tid & 127, h = tid >> 7;
    float acc = 0.f;
    for (int m = 0; m < NN_; ++m) acc += arow[h][m] * Qn[m * KKc + r];
    QfQn[(n0 + h) * KKc + r] = acc;
  } else if (w < 160) {
    __shared__ float wcol[2][NN_];
    const int c0 = 2 * (w - 128);
    for (int idx = tid; idx < 2 * NN_; idx += 256)
      wcol[idx >> 8][idx & 255] = Wf[(idx & 255) * PP_ + c0 + (idx >> 8)];
    __syncthreads();
    const int r = tid & 127, h = tid >> 7;
    float acc = 0.f;
    for (int n = 0; n < NN_; ++n) acc += wcol[h][n] * Qn[n * KKc + r];
    WfQn[(c0 + h) * KKc + r] = acc;
  } else if (w < 672) {
    __shared__ float BpP[MM_ * 65];
    __shared__ float pr[2][PP_];
    const int b0 = 2 * (w - 160);
    for (int idx = tid; idx < MM_ * PP_; idx += 256) {
      int m = idx >> 6, p = idx & 63;
      BpP[m * 65 + p] = Bp[idx];
    }
    for (int idx = tid; idx < 2 * PP_; idx += 256)
      pr[idx >> 6][idx & 63] = parms[(b0 + (idx >> 6)) * PP_ + (idx & 63)];
    __syncthreads();
    const int m = tid & 127, h = tid >> 7;
    float acc = 0.f;
    for (int p = 0; p < PP_; ++p) acc += pr[h][p] * BpP[m * 65 + p];
    bb[(b0 + h) * MM_ + m] = acc;
  } else {
    const int mm = w - 672;
    QrT[mm * NN_ + tid] = Qr[tid * MM_ + mm];
  }
}

// ---------------------------------------------------------------------------
// k_pre3: C = Qn.T @ QfQn (128x128)  |  batched forward-sub: bb <- zeta_r
//         (in place), 64 batches per wg
// ---------------------------------------------------------------------------
__global__ __launch_bounds__(256) void k_pre3(
    const float* __restrict__ Qn, const float* __restrict__ QfQn,
    const float* __restrict__ Rr, float* __restrict__ C, float* __restrict__ bb)
{
  const int w = blockIdx.x, tid = threadIdx.x;
  if (w < 64) {
    __shared__ float qcol[2][NN_];
    const int r0 = 2 * w;
    for (int idx = tid; idx < 2 * NN_; idx += 256)
      qcol[idx >> 8][idx & 255] = Qn[(idx & 255) * KKc + r0 + (idx >> 8)];
    __syncthreads();
    const int s = tid & 127, h = tid >> 7;
    float acc = 0.f;
    for (int n = 0; n < NN_; ++n) acc += qcol[h][n] * QfQn[n * KKc + s];
    C[(r0 + h) * KKc + s] = acc;
  } else {
    __shared__ float Wt[MM_ * 65];
    const int b0 = (w - 64) * 64;
    for (int idx = tid; idx < 64 * MM_; idx += 256) {
      int b = idx >> 7, m = idx & 127;
      Wt[m * 65 + b] = bb[(b0 + b) * MM_ + m];
    }
    __syncthreads();
    const int c = tid & 63, q = tid >> 6;
    if (q == 0) Wt[0 * 65 + c] /= Rr[0];
    for (int i = 0; i < MM_; ++i) {
      __syncthreads();
      float xi = Wt[i * 65 + c];
      for (int k = i + 1 + q; k < MM_; k += 4) {
        float v = Wt[k * 65 + c] - Rr[i * MM_ + k] * xi;
        if (k == i + 1) v /= Rr[k * MM_ + k];
        Wt[k * 65 + c] = v;
      }
    }
    __syncthreads();
    for (int idx = tid; idx < 64 * MM_; idx += 256) {
      int b = idx >> 7, m = idx & 127;
      bb[(b0 + b) * MM_ + m] = Wt[m * 65 + b];
    }
  }
}

// ---------------------------------------------------------------------------
// k_vec: per batch: zeta = zeta_r @ Qr.T ; t = (1+x^2)(x - zeta)
//        rhs = t@Qn - zeta@QfQn - parms@WfQn      (2 batches per wg)
// ---------------------------------------------------------------------------
__global__ __launch_bounds__(256) void k_vec(
    const float* __restrict__ x, const float* __restrict__ parms,
    const float* __restrict__ zr, const float* __restrict__ QrT,
    const float* __restrict__ Qn, const float* __restrict__ QfQn,
    const float* __restrict__ WfQn,
    float* __restrict__ zeta, float* __restrict__ rhs)
{
  const int b0 = blockIdx.x * 2, tid = threadIdx.x;
  __shared__ float zrL[2][MM_], pL[2][PP_], xL[2][NN_], zL[2][NN_], tL[2][NN_];
  for (int idx = tid; idx < 2 * MM_; idx += 256)
    zrL[idx >> 7][idx & 127] = zr[(b0 + (idx >> 7)) * MM_ + (idx & 127)];
  for (int idx = tid; idx < 2 * PP_; idx += 256)
    pL[idx >> 6][idx & 63] = parms[(b0 + (idx >> 6)) * PP_ + (idx & 63)];
  for (int idx = tid; idx < 2 * NN_; idx += 256)
    xL[idx >> 8][idx & 255] = x[(b0 + (idx >> 8)) * NN_ + (idx & 255)];
  __syncthreads();
  {
    const int n = tid;
    float a0 = 0.f, a1 = 0.f;
    for (int m = 0; m < MM_; ++m) {
      float qv = QrT[m * NN_ + n];
      a0 += zrL[0][m] * qv;
      a1 += zrL[1][m] * qv;
    }
    float x0 = xL[0][n], x1 = xL[1][n];
    zL[0][n] = a0; zL[1][n] = a1;
    float t0 = (1.f + x0 * x0) * (x0 - a0);
    float t1 = (1.f + x1 * x1) * (x1 - a1);
    tL[0][n] = t0; tL[1][n] = t1;
    zeta[b0 * NN_ + n] = a0;
    zeta[(b0 + 1) * NN_ + n] = a1;
  }
  __syncthreads();
  {
    const int r = tid & 127, h = tid >> 7;
    float acc = 0.f;
    for (int n = 0; n < NN_; ++n) acc += tL[h][n] * Qn[n * KKc + r];
    for (int n = 0; n < NN_; ++n) acc -= zL[h][n] * QfQn[n * KKc + r];
    for (int c = 0; c < PP_; ++c) acc -= pL[h][c] * WfQn[c * KKc + r];
    rhs[(b0 + h) * KKc + r] = acc;
  }
}

// ---------------------------------------------------------------------------
// k_main: one wg per batch.
//  S = C + Qs^T Qs (Qs = sqrt(1+x^2) * Qn rows), reg-tiled 8x8, S -> LDS[128][132]
//  blocked Cholesky NB=8 (redundant diag factor, register panels),
//  single-wave fwd/bwd solves, x_new = Qn z + zeta.
// ---------------------------------------------------------------------------
__global__ __launch_bounds__(256, 2) void k_main(
    const float* __restrict__ x, const float* __restrict__ Qn,
    const float* __restrict__ C, const float* __restrict__ rhs,
    const float* __restrict__ zeta, float* __restrict__ out)
{
  const int b = blockIdx.x, tid = threadIdx.x;
  __shared__ __align__(16) float SH[128 * 132];   // phase1: Qs[64][128] ; phase2: S[128][132]
  __shared__ __align__(16) float sd[NN_];
  __shared__ __align__(16) float fbuf[MM_];
  const int tx = tid & 15, ty = tid >> 4;

  {
    float xv = x[b * NN_ + tid];
    sd[tid] = sqrtf(1.f + xv * xv);
  }
  __syncthreads();

  float acc[8][8];
#pragma unroll
  for (int i = 0; i < 8; ++i) {
    const float4* c4 = reinterpret_cast<const float4*>(&C[(ty * 8 + i) * KKc + tx * 8]);
    float4 v0 = c4[0], v1 = c4[1];
    acc[i][0] = v0.x; acc[i][1] = v0.y; acc[i][2] = v0.z; acc[i][3] = v0.w;
    acc[i][4] = v1.x; acc[i][5] = v1.y; acc[i][6] = v1.z; acc[i][7] = v1.w;
  }

  for (int c0 = 0; c0 < NN_; c0 += 64) {
    __syncthreads();
    for (int idx = tid; idx < 2048; idx += 256) {   // 64x128 floats as float4
      int row = idx >> 5, c4i = idx & 31;
      float4 q = reinterpret_cast<const float4*>(Qn)[(c0 + row) * 32 + c4i];
      float s = sd[c0 + row];
      q.x *= s; q.y *= s; q.z *= s; q.w *= s;
      reinterpret_cast<float4*>(SH)[row * 32 + c4i] = q;
    }
    __syncthreads();
    for (int i = 0; i < 64; ++i) {
      const float4* qr4 = reinterpret_cast<const float4*>(&SH[i * KKc + ty * 8]);
      const float4* qs4 = reinterpret_cast<const float4*>(&SH[i * KKc + tx * 8]);
      float4 r0 = qr4[0], r1 = qr4[1], s0 = qs4[0], s1 = qs4[1];
      float qr[8] = {r0.x, r0.y, r0.z, r0.w, r1.x, r1.y, r1.z, r1.w};
      float qs[8] = {s0.x, s0.y, s0.z, s0.w, s1.x, s1.y, s1.z, s1.w};
#pragma unroll
      for (int a = 0; a < 8; ++a)
#pragma unroll
        for (int d2 = 0; d2 < 8; ++d2) acc[a][d2] += qr[a] * qs[d2];
    }
  }
  __syncthreads();

#pragma unroll
  for (int i = 0; i < 8; ++i) {
    float4 v0 = {acc[i][0], acc[i][1], acc[i][2], acc[i][3]};
    float4 v1 = {acc[i][4], acc[i][5], acc[i][6], acc[i][7]};
    float* rowp = &SH[(ty * 8 + i) * 132 + tx * 8];
    reinterpret_cast<float4*>(rowp)[0] = v0;
    reinterpret_cast<float4*>(rowp)[1] = v1;
  }
  if (tid < MM_) fbuf[tid] = rhs[b * MM_ + tid];
  __syncthreads();

  // ---- blocked Cholesky, NB = 8 ----
  for (int kb = 0; kb < 16; ++kb) {
    const int k0 = kb * 8;
    float D[8][8];
#pragma unroll
    for (int i = 0; i < 8; ++i)
#pragma unroll
      for (int j = 0; j <= i; ++j) D[i][j] = SH[(k0 + i) * 132 + k0 + j];
#pragma unroll
    for (int j = 0; j < 8; ++j) {
      float dj = sqrtf(D[j][j]);
      float rj = 1.f / dj;
      D[j][j] = dj;
#pragma unroll
      for (int i = j + 1; i < 8; ++i) D[i][j] *= rj;
#pragma unroll
      for (int i = j + 1; i < 8; ++i)
#pragma unroll
        for (int t2 = j + 1; t2 <= i; ++t2) D[i][t2] -= D[i][j] * D[t2][j];
    }
    if (ty == kb && tx == kb) {
#pragma unroll
      for (int i = 0; i < 8; ++i)
#pragma unroll
        for (int j = 0; j <= i; ++j) SH[(k0 + i) * 132 + k0 + j] = D[i][j];
    }
    if (tx == kb && ty > kb) {
      float rD[8];
#pragma unroll
      for (int j = 0; j < 8; ++j) rD[j] = 1.f / D[j][j];
#pragma unroll
      for (int rr = 0; rr < 8; ++rr) {
        float a[8];
        float* rp = &SH[(ty * 8 + rr) * 132 + k0];
#pragma unroll
        for (int j = 0; j < 8; ++j) a[j] = rp[j];
#pragma unroll
        for (int j = 0; j < 8; ++j) {
          float v = a[j];
#pragma unroll
          for (int t2 = 0; t2 < j; ++t2) v -= a[t2] * D[j][t2];
          a[j] = v * rD[j];
        }
#pragma unroll
        for (int j = 0; j < 8; ++j) rp[j] = a[j];
      }
    }
    __syncthreads();
    if (ty > kb && tx > kb && ty >= tx) {
      float Pj[8][8];
#pragma unroll
      for (int cc = 0; cc < 8; ++cc) {
        const float4* p4 = reinterpret_cast<const float4*>(&SH[(tx * 8 + cc) * 132 + k0]);
        float4 v0 = p4[0], v1 = p4[1];
        Pj[cc][0] = v0.x; Pj[cc][1] = v0.y; Pj[cc][2] = v0.z; Pj[cc][3] = v0.w;
        Pj[cc][4] = v1.x; Pj[cc][5] = v1.y; Pj[cc][6] = v1.z; Pj[cc][7] = v1.w;
      }
#pragma unroll
      for (int rr = 0; rr < 8; ++rr) {
        const float4* pi4 = reinterpret_cast<const float4*>(&SH[(ty * 8 + rr) * 132 + k0]);
        float4 a0 = pi4[0], a1 = pi4[1];
        float Pi[8] = {a0.x, a0.y, a0.z, a0.w, a1.x, a1.y, a1.z, a1.w};
        float* trow = &SH[(ty * 8 + rr) * 132 + tx * 8];
        float4 t0 = reinterpret_cast<float4*>(trow)[0];
        float4 t1 = reinterpret_cast<float4*>(trow)[1];
        float T[8] = {t0.x, t0.y, t0.z, t0.w, t1.x, t1.y, t1.z, t1.w};
#pragma unroll
        for (int cc = 0; cc < 8; ++cc) {
          float s2 = 0.f;
#pragma unroll
          for (int t2 = 0; t2 < 8; ++t2) s2 += Pi[t2] * Pj[cc][t2];
          T[cc] -= s2;
        }
        float4 w0 = {T[0], T[1], T[2], T[3]}, w1 = {T[4], T[5], T[6], T[7]};
        reinterpret_cast<float4*>(trow)[0] = w0;
        reinterpret_cast<float4*>(trow)[1] = w1;
      }
    }
    __syncthreads();
  }

  // ---- triangular solves on wave 0 ----
  if (tid < 64) {
    const int l = tid;
    for (int k2 = 0; k2 < MM_; ++k2) {
      float yk = fbuf[k2] / SH[k2 * 132 + k2];
      if (l > k2) fbuf[l] -= SH[l * 132 + k2] * yk;
      int l2 = l + 64;
      if (l2 > k2) fbuf[l2] -= SH[l2 * 132 + k2] * yk;
      if (l == 0) fbuf[k2] = yk;
    }
    for (int k2 = MM_ - 1; k2 >= 0; --k2) {
      float zk = fbuf[k2] / SH[k2 * 132 + k2];
      if (l < k2) fbuf[l] -= SH[k2 * 132 + l] * zk;
      int l2 = l + 64;
      if (l2 < k2) fbuf[l2] -= SH[k2 * 132 + l2] * zk;
      if (l == 0) fbuf[k2] = zk;
    }
  }
  __syncthreads();

  {
    const int n = tid;
    float a2 = zeta[b * NN_ + n];
    const float4* qrow = reinterpret_cast<const float4*>(&Qn[n * KKc]);
    for (int rq = 0; rq < 32; ++rq) {
      float4 q = qrow[rq];
      float4 z4 = reinterpret_cast<const float4*>(fbuf)[rq];
      a2 += q.x * z4.x + q.y * z4.y + q.z * z4.z + q.w * z4.w;
    }
    out[b * NN_ + n] = a2;
  }
}

// ---------------------------------------------------------------------------
extern "C" void kernel_launch(void* const* d_in, const int* in_sizes, int n_in,
                              void* d_out, int out_size, void* d_ws, size_t ws_size,
                              hipStream_t stream)
{
  const float* x     = (const float*)d_in[0];
  const float* parms = (const float*)d_in[1];
  // d_in[2] = A : unused (cancels algebraically)
  const float* Bp    = (const float*)d_in[3];
  const float* Qf    = (const float*)d_in[4];
  const float* Wf    = (const float*)d_in[5];
  const float* Qr    = (const float*)d_in[6];
  const float* Qn    = (const float*)d_in[7];
  const float* Rr    = (const float*)d_in[8];

  float* ws   = (float*)d_ws;
  float* QfQn = ws;                 // 256*128 = 32768
  float* WfQn = QfQn + 32768;       // 64*128  = 8192
  float* bb   = WfQn + 8192;        // 1024*128 = 131072 (bb -> zeta_r in place)
  float* QrT  = bb + 131072;        // 128*256 = 32768
  float* Cm   = QrT + 32768;        // 128*128 = 16384
  float* zeta = Cm + 16384;         // 1024*256 = 262144
  float* rhs  = zeta + 262144;      // 1024*128 = 131072

  float* outp = (float*)d_out;

  hipLaunchKernelGGL(k_pre2, dim3(800), dim3(256), 0, stream,
                     Qf, Qn, Wf, parms, Bp, Qr, QfQn, WfQn, bb, QrT);
  hipLaunchKernelGGL(k_pre3, dim3(80), dim3(256), 0, stream,
                     Qn, QfQn, Rr, Cm, bb);
  hipLaunchKernelGGL(k_vec, dim3(512), dim3(256), 0, stream,
                     x, parms, bb, QrT, Qn, QfQn, WfQn, zeta, rhs);
  hipLaunchKernelGGL(k_main, dim3(1024), dim3(256), 0, stream,
                     x, Qn, Cm, rhs, zeta, outp);
}